// Round 1
// baseline (1362.468 us; speedup 1.0000x reference)
//
#include <hip/hip_runtime.h>
#include <hip/hip_bf16.h>

#define T_TOK 1024
#define DDIM  1024
#define FDIM  2048
#define NEXP  16

// ---------------- workspace layout (bytes) ----------------
// [0, 64)            : int cnt[NEXP]            (memset to 0 each call)
// [1024, +64K)       : int   entry[NEXP][T_TOK]   (value = t*2 + slot)
// [66560, +64K)      : float entry_w[NEXP][T_TOK]
// [132096, +16M)     : float fuse[2*T_TOK][FDIM]
// [16909312, +8M)    : float partial[2][T_TOK][DDIM]
#define WS_ENTRY_OFF   1024
#define WS_ENTRYW_OFF  66560
#define WS_FUSE_OFF    132096
#define WS_PART_OFF    16909312

// ---------------- router: one block (64 thr) per token ----------------
__global__ __launch_bounds__(64) void router_kernel(
    const float* __restrict__ x, const float* __restrict__ rw,
    int* __restrict__ cnt, int* __restrict__ entry, float* __restrict__ entry_w)
{
    const int t = blockIdx.x;
    const int lane = threadIdx.x;   // 0..63
    float acc[NEXP];
#pragma unroll
    for (int e = 0; e < NEXP; ++e) acc[e] = 0.f;
#pragma unroll
    for (int i = 0; i < DDIM / 64; ++i) {
        const int d = lane + i * 64;
        const float xv = x[(size_t)t * DDIM + d];
        const float* r = rw + (size_t)d * NEXP;
#pragma unroll
        for (int e = 0; e < NEXP; ++e) acc[e] += xv * r[e];
    }
#pragma unroll
    for (int e = 0; e < NEXP; ++e) {
        float v = acc[e];
        for (int off = 32; off > 0; off >>= 1) v += __shfl_down(v, off);
        acc[e] = v;
    }
    if (lane == 0) {
        int i0 = -1, i1 = -1;
        float v0 = -1e30f, v1 = -1e30f;
#pragma unroll
        for (int e = 0; e < NEXP; ++e) {
            const float v = acc[e];
            if (v > v0)      { v1 = v0; i1 = i0; v0 = v; i0 = e; }
            else if (v > v1) { v1 = v;  i1 = e; }
        }
        // softmax + renorm over top-2: denominators cancel
        const float e1 = __expf(v1 - v0);
        const float w0 = 1.f / (1.f + e1);
        const float w1 = e1 / (1.f + e1);
        int p = atomicAdd(&cnt[i0], 1);
        entry[i0 * T_TOK + p] = t * 2 + 0;
        entry_w[i0 * T_TOK + p] = w0;
        p = atomicAdd(&cnt[i1], 1);
        entry[i1 * T_TOK + p] = t * 2 + 1;
        entry_w[i1 * T_TOK + p] = w1;
    }
}

// ---------------- phase 1: gating+up GEMM + silu-fuse ----------------
// grid (NEXP, FDIM/128, 8 m-tiles), block 256. BM=128, BN=128, BK=32.
__global__ __launch_bounds__(256) void ffn1_kernel(
    const float* __restrict__ x,
    const float* __restrict__ wg, const float* __restrict__ wu,
    const int* __restrict__ cnt, const int* __restrict__ entry,
    float* __restrict__ fuse)
{
    const int e  = blockIdx.x;
    const int f0 = blockIdx.y * 128;
    const int m0 = blockIdx.z * 128;
    const int n_tok = cnt[e];
    if (m0 >= n_tok) return;

    __shared__ float xs[128][33];
    __shared__ float bgs[32][128];
    __shared__ float bus[32][128];
    __shared__ int   stok[128];
    __shared__ int   sem[128];

    const int tid = threadIdx.x;
    const int tn = tid & 15;
    const int tm = tid >> 4;

    const float* wg_e = wg + (size_t)e * DDIM * FDIM;
    const float* wu_e = wu + (size_t)e * DDIM * FDIM;

    if (tid < 128) {
        const int i = m0 + tid;
        const int em = (i < n_tok) ? entry[e * T_TOK + i] : -1;
        sem[tid]  = em;
        stok[tid] = (em >= 0) ? (em >> 1) : 0;
    }
    __syncthreads();

    float acc_g[8][8], acc_u[8][8];
#pragma unroll
    for (int a = 0; a < 8; ++a)
#pragma unroll
        for (int b = 0; b < 8; ++b) { acc_g[a][b] = 0.f; acc_u[a][b] = 0.f; }

    for (int kk = 0; kk < DDIM; kk += 32) {
        // stage x tile: 128 rows x 32 cols
#pragma unroll
        for (int j = 0; j < 4; ++j) {
            const int L = tid + 256 * j;
            const int r = L >> 3;
            const int c = (L & 7) * 4;
            const float4 v = *(const float4*)(x + (size_t)stok[r] * DDIM + kk + c);
            xs[r][c + 0] = v.x; xs[r][c + 1] = v.y; xs[r][c + 2] = v.z; xs[r][c + 3] = v.w;
        }
        // stage W tiles: 32 rows x 128 cols
#pragma unroll
        for (int j = 0; j < 4; ++j) {
            const int L = tid + 256 * j;
            const int r = L >> 5;
            const int c = (L & 31) * 4;
            const float4 vg = *(const float4*)(wg_e + (size_t)(kk + r) * FDIM + f0 + c);
            const float4 vu = *(const float4*)(wu_e + (size_t)(kk + r) * FDIM + f0 + c);
            *(float4*)&bgs[r][c] = vg;
            *(float4*)&bus[r][c] = vu;
        }
        __syncthreads();
#pragma unroll
        for (int k = 0; k < 32; ++k) {
            float a[8], bg[8], bu[8];
#pragma unroll
            for (int im = 0; im < 8; ++im) a[im] = xs[tm + 16 * im][k];
#pragma unroll
            for (int in = 0; in < 8; ++in) { bg[in] = bgs[k][tn + 16 * in]; bu[in] = bus[k][tn + 16 * in]; }
#pragma unroll
            for (int im = 0; im < 8; ++im)
#pragma unroll
                for (int in = 0; in < 8; ++in) {
                    acc_g[im][in] += a[im] * bg[in];
                    acc_u[im][in] += a[im] * bu[in];
                }
        }
        __syncthreads();
    }

#pragma unroll
    for (int im = 0; im < 8; ++im) {
        const int m = tm + 16 * im;
        const int em = sem[m];
        if (em < 0) continue;
        float* dst = fuse + (size_t)em * FDIM + f0;
#pragma unroll
        for (int in = 0; in < 8; ++in) {
            const float g = acc_g[im][in];
            const float h = (g / (1.f + __expf(-g))) * acc_u[im][in];
            dst[tn + 16 * in] = h;
        }
    }
}

// ---------------- phase 2: down GEMM, weighted, into partial ----------------
// grid (NEXP, DDIM/128, 8 m-tiles), block 256. BM=128, BN=128, BK=32.
__global__ __launch_bounds__(256) void ffn2_kernel(
    const float* __restrict__ fuse, const float* __restrict__ wd,
    const int* __restrict__ cnt, const int* __restrict__ entry,
    const float* __restrict__ entry_w, float* __restrict__ partial)
{
    const int e  = blockIdx.x;
    const int d0 = blockIdx.y * 128;
    const int m0 = blockIdx.z * 128;
    const int n_tok = cnt[e];
    if (m0 >= n_tok) return;

    __shared__ float as[128][33];
    __shared__ float bs[32][128];
    __shared__ int   sem[128];
    __shared__ float sw[128];

    const int tid = threadIdx.x;
    const int tn = tid & 15;
    const int tm = tid >> 4;

    const float* wd_e = wd + (size_t)e * FDIM * DDIM;

    if (tid < 128) {
        const int i = m0 + tid;
        sem[tid] = (i < n_tok) ? entry[e * T_TOK + i] : -1;
        sw[tid]  = (i < n_tok) ? entry_w[e * T_TOK + i] : 0.f;
    }
    __syncthreads();

    float acc[8][8];
#pragma unroll
    for (int a = 0; a < 8; ++a)
#pragma unroll
        for (int b = 0; b < 8; ++b) acc[a][b] = 0.f;

    for (int kk = 0; kk < FDIM; kk += 32) {
#pragma unroll
        for (int j = 0; j < 4; ++j) {
            const int L = tid + 256 * j;
            const int r = L >> 3;
            const int c = (L & 7) * 4;
            const int em = sem[r] >= 0 ? sem[r] : 0;
            const float4 v = *(const float4*)(fuse + (size_t)em * FDIM + kk + c);
            as[r][c + 0] = v.x; as[r][c + 1] = v.y; as[r][c + 2] = v.z; as[r][c + 3] = v.w;
        }
#pragma unroll
        for (int j = 0; j < 4; ++j) {
            const int L = tid + 256 * j;
            const int r = L >> 5;
            const int c = (L & 31) * 4;
            const float4 v = *(const float4*)(wd_e + (size_t)(kk + r) * DDIM + d0 + c);
            *(float4*)&bs[r][c] = v;
        }
        __syncthreads();
#pragma unroll
        for (int k = 0; k < 32; ++k) {
            float a[8], b[8];
#pragma unroll
            for (int im = 0; im < 8; ++im) a[im] = as[tm + 16 * im][k];
#pragma unroll
            for (int in = 0; in < 8; ++in) b[in] = bs[k][tn + 16 * in];
#pragma unroll
            for (int im = 0; im < 8; ++im)
#pragma unroll
                for (int in = 0; in < 8; ++in) acc[im][in] += a[im] * b[in];
        }
        __syncthreads();
    }

#pragma unroll
    for (int im = 0; im < 8; ++im) {
        const int m = tm + 16 * im;
        const int em = sem[m];
        if (em < 0) continue;
        const int t = em >> 1;
        const int slot = em & 1;
        const float w = sw[m];
        float* dst = partial + ((size_t)slot * T_TOK + t) * DDIM + d0;
#pragma unroll
        for (int in = 0; in < 8; ++in) dst[tn + 16 * in] = acc[im][in] * w;
    }
}

// ---------------- phase 3: out = partial[0] + partial[1] ----------------
__global__ __launch_bounds__(256) void add_kernel(
    const float* __restrict__ partial, float* __restrict__ out)
{
    const int i = blockIdx.x * blockDim.x + threadIdx.x;   // over T*D/4
    const float4 a = ((const float4*)partial)[i];
    const float4 b = ((const float4*)(partial + (size_t)T_TOK * DDIM))[i];
    float4 o;
    o.x = a.x + b.x; o.y = a.y + b.y; o.z = a.z + b.z; o.w = a.w + b.w;
    ((float4*)out)[i] = o;
}

extern "C" void kernel_launch(void* const* d_in, const int* in_sizes, int n_in,
                              void* d_out, int out_size, void* d_ws, size_t ws_size,
                              hipStream_t stream) {
    const float* x  = (const float*)d_in[0];
    const float* rw = (const float*)d_in[1];
    const float* wg = (const float*)d_in[2];
    const float* wu = (const float*)d_in[3];
    const float* wd = (const float*)d_in[4];
    float* out = (float*)d_out;

    char* ws = (char*)d_ws;
    int*   cnt     = (int*)ws;
    int*   entry   = (int*)(ws + WS_ENTRY_OFF);
    float* entry_w = (float*)(ws + WS_ENTRYW_OFF);
    float* fuse    = (float*)(ws + WS_FUSE_OFF);
    float* partial = (float*)(ws + WS_PART_OFF);

    hipMemsetAsync(cnt, 0, 1024, stream);

    router_kernel<<<T_TOK, 64, 0, stream>>>(x, rw, cnt, entry, entry_w);

    ffn1_kernel<<<dim3(NEXP, FDIM / 128, 8), 256, 0, stream>>>(
        x, wg, wu, cnt, entry, fuse);

    ffn2_kernel<<<dim3(NEXP, DDIM / 128, 8), 256, 0, stream>>>(
        fuse, wd, cnt, entry, entry_w, partial);

    add_kernel<<<(T_TOK * DDIM / 4) / 256, 256, 0, stream>>>(partial, out);
}

// Round 2
// 523.827 us; speedup vs baseline: 2.6010x; 2.6010x over previous
//
#include <hip/hip_runtime.h>
#include <hip/hip_bf16.h>

typedef __bf16 bf16_t;
typedef __bf16 bf16x8 __attribute__((ext_vector_type(8)));
typedef float  f32x4  __attribute__((ext_vector_type(4)));

#define T_TOK 1024
#define DDIM  1024
#define FDIM  2048
#define NEXP  16

// ---------------- workspace layout (bytes) ----------------
// [0, 64)       : int cnt[NEXP]            (memset to 0 each call)
// [1024, +64K)  : int   entry[NEXP][T_TOK]   (value = t*2 + slot)
// [66560, +64K) : float entry_w[NEXP][T_TOK]
// [132096, +8M) : bf16  fuse[2*T_TOK][FDIM]
// [+8M, +8M)    : float partial[2][T_TOK][DDIM]
#define WS_ENTRY_OFF   1024
#define WS_ENTRYW_OFF  66560
#define WS_FUSE_OFF    132096
#define WS_PART_OFF    (132096 + 8388608)

__device__ inline bf16x8 pack8(const float4& a, const float4& b) {
    bf16x8 p;
    p[0] = (bf16_t)a.x; p[1] = (bf16_t)a.y; p[2] = (bf16_t)a.z; p[3] = (bf16_t)a.w;
    p[4] = (bf16_t)b.x; p[5] = (bf16_t)b.y; p[6] = (bf16_t)b.z; p[7] = (bf16_t)b.w;
    return p;
}

// ---------------- router: one block (64 thr) per token ----------------
__global__ __launch_bounds__(64) void router_kernel(
    const float* __restrict__ x, const float* __restrict__ rw,
    int* __restrict__ cnt, int* __restrict__ entry, float* __restrict__ entry_w)
{
    const int t = blockIdx.x;
    const int lane = threadIdx.x;   // 0..63
    float acc[NEXP];
#pragma unroll
    for (int e = 0; e < NEXP; ++e) acc[e] = 0.f;
#pragma unroll
    for (int i = 0; i < DDIM / 64; ++i) {
        const int d = lane + i * 64;
        const float xv = x[(size_t)t * DDIM + d];
        const float* r = rw + (size_t)d * NEXP;
#pragma unroll
        for (int e = 0; e < NEXP; ++e) acc[e] += xv * r[e];
    }
#pragma unroll
    for (int e = 0; e < NEXP; ++e) {
        float v = acc[e];
        for (int off = 32; off > 0; off >>= 1) v += __shfl_down(v, off);
        acc[e] = v;
    }
    if (lane == 0) {
        int i0 = -1, i1 = -1;
        float v0 = -1e30f, v1 = -1e30f;
#pragma unroll
        for (int e = 0; e < NEXP; ++e) {
            const float v = acc[e];
            if (v > v0)      { v1 = v0; i1 = i0; v0 = v; i0 = e; }
            else if (v > v1) { v1 = v;  i1 = e; }
        }
        const float e1 = __expf(v1 - v0);
        const float w0 = 1.f / (1.f + e1);
        const float w1 = e1 / (1.f + e1);
        int p = atomicAdd(&cnt[i0], 1);
        entry[i0 * T_TOK + p] = t * 2 + 0;
        entry_w[i0 * T_TOK + p] = w0;
        p = atomicAdd(&cnt[i1], 1);
        entry[i1 * T_TOK + p] = t * 2 + 1;
        entry_w[i1 * T_TOK + p] = w1;
    }
}

// ---------------- phase 1: gating+up MFMA GEMM + silu-fuse ----------------
// grid (NEXP, FDIM/64, 4), block 256. BM=256, BN=64, BK=32. bf16 MFMA.
__global__ __launch_bounds__(256) void ffn1_kernel(
    const float* __restrict__ x,
    const float* __restrict__ wg, const float* __restrict__ wu,
    const int* __restrict__ cnt, const int* __restrict__ entry,
    bf16_t* __restrict__ fuse)
{
    const int e  = blockIdx.x;
    const int f0 = blockIdx.y * 64;
    const int m0 = blockIdx.z * 256;
    const int n_tok = cnt[e];
    if (m0 >= n_tok) return;

    __shared__ bf16_t As[256][40];   // [m][k], k-contiguous, 16B-aligned rows
    __shared__ bf16_t Bgs[64][40];   // [n][k]
    __shared__ bf16_t Bus[64][40];   // [n][k]
    __shared__ int    stok[256];
    __shared__ int    sem[256];

    const int tid  = threadIdx.x;
    const int wave = tid >> 6;
    const int lane = tid & 63;
    const int r    = lane & 15;   // row/col within MFMA tile
    const int q    = lane >> 4;   // k-quad

    const float* wg_e = wg + (size_t)e * DDIM * FDIM;
    const float* wu_e = wu + (size_t)e * DDIM * FDIM;

    {
        const int i = m0 + tid;
        const int em = (i < n_tok) ? entry[e * T_TOK + i] : -1;
        sem[tid]  = em;
        stok[tid] = (em >= 0) ? (em >> 1) : 0;
    }
    __syncthreads();

    f32x4 accg[4][4], accu[4][4];
#pragma unroll
    for (int a = 0; a < 4; ++a)
#pragma unroll
        for (int b = 0; b < 4; ++b) {
            accg[a][b] = (f32x4){0.f, 0.f, 0.f, 0.f};
            accu[a][b] = (f32x4){0.f, 0.f, 0.f, 0.f};
        }

    const float* xr_base = x + (size_t)stok[tid] * DDIM;

    for (int kk = 0; kk < DDIM; kk += 32) {
        // ---- stage A (x gather): one row per thread, 32 floats -> bf16 ----
        {
            const float4* xr = (const float4*)(xr_base + kk);
            float4 v0 = xr[0], v1 = xr[1], v2 = xr[2], v3 = xr[3];
            float4 v4 = xr[4], v5 = xr[5], v6 = xr[6], v7 = xr[7];
            *(bf16x8*)&As[tid][0]  = pack8(v0, v1);
            *(bf16x8*)&As[tid][8]  = pack8(v2, v3);
            *(bf16x8*)&As[tid][16] = pack8(v4, v5);
            *(bf16x8*)&As[tid][24] = pack8(v6, v7);
        }
        // ---- stage Bg/Bu: lane = n (0..63), wave = k-group of 8 ----
        {
            const size_t base = (size_t)(kk + wave * 8) * FDIM + f0 + lane;
            const float* gp = wg_e + base;
            const float* up = wu_e + base;
            bf16x8 pg, pu;
#pragma unroll
            for (int j = 0; j < 8; ++j) {
                pg[j] = (bf16_t)gp[(size_t)j * FDIM];
                pu[j] = (bf16_t)up[(size_t)j * FDIM];
            }
            *(bf16x8*)&Bgs[lane][wave * 8] = pg;
            *(bf16x8*)&Bus[lane][wave * 8] = pu;
        }
        __syncthreads();

        bf16x8 af[4];
#pragma unroll
        for (int mt = 0; mt < 4; ++mt)
            af[mt] = *(const bf16x8*)&As[wave * 64 + mt * 16 + r][q * 8];
        bf16x8 bg[4], bu[4];
#pragma unroll
        for (int nt = 0; nt < 4; ++nt) {
            bg[nt] = *(const bf16x8*)&Bgs[nt * 16 + r][q * 8];
            bu[nt] = *(const bf16x8*)&Bus[nt * 16 + r][q * 8];
        }
#pragma unroll
        for (int mt = 0; mt < 4; ++mt)
#pragma unroll
            for (int nt = 0; nt < 4; ++nt) {
                accg[mt][nt] = __builtin_amdgcn_mfma_f32_16x16x32_bf16(af[mt], bg[nt], accg[mt][nt], 0, 0, 0);
                accu[mt][nt] = __builtin_amdgcn_mfma_f32_16x16x32_bf16(af[mt], bu[nt], accu[mt][nt], 0, 0, 0);
            }
        __syncthreads();
    }

    // ---- epilogue: silu(g)*u -> fuse (bf16) ----
#pragma unroll
    for (int mt = 0; mt < 4; ++mt) {
#pragma unroll
        for (int j = 0; j < 4; ++j) {
            const int m = wave * 64 + mt * 16 + q * 4 + j;
            const int em = sem[m];
            if (em < 0) continue;
            bf16_t* dst = fuse + (size_t)em * FDIM + f0;
#pragma unroll
            for (int nt = 0; nt < 4; ++nt) {
                const float g = accg[mt][nt][j];
                const float u = accu[mt][nt][j];
                const float h = (g / (1.f + __expf(-g))) * u;
                dst[nt * 16 + r] = (bf16_t)h;
            }
        }
    }
}

// ---------------- phase 2: down MFMA GEMM, weighted -> partial ----------------
// grid (NEXP, DDIM/32, 4), block 256. BM=256, BN=32, BK=32.
__global__ __launch_bounds__(256) void ffn2_kernel(
    const bf16_t* __restrict__ fuse, const float* __restrict__ wd,
    const int* __restrict__ cnt, const int* __restrict__ entry,
    const float* __restrict__ entry_w, float* __restrict__ partial)
{
    const int e  = blockIdx.x;
    const int d0 = blockIdx.y * 32;
    const int m0 = blockIdx.z * 256;
    const int n_tok = cnt[e];
    if (m0 >= n_tok) return;

    __shared__ bf16_t As[256][40];   // [m][k]
    __shared__ bf16_t Bs[32][40];    // [n][k]
    __shared__ int    sem[256];
    __shared__ float  sw[256];

    const int tid  = threadIdx.x;
    const int wave = tid >> 6;
    const int lane = tid & 63;
    const int r    = lane & 15;
    const int q    = lane >> 4;

    const float* wd_e = wd + (size_t)e * FDIM * DDIM;

    {
        const int i = m0 + tid;
        const int em = (i < n_tok) ? entry[e * T_TOK + i] : -1;
        sem[tid] = em;
        sw[tid]  = (i < n_tok) ? entry_w[e * T_TOK + i] : 0.f;
    }
    __syncthreads();

    const bf16_t* frow = fuse + (size_t)(sem[tid] >= 0 ? sem[tid] : 0) * FDIM;

    f32x4 acc[4][2];
#pragma unroll
    for (int a = 0; a < 4; ++a)
#pragma unroll
        for (int b = 0; b < 2; ++b) acc[a][b] = (f32x4){0.f, 0.f, 0.f, 0.f};

    for (int kk = 0; kk < FDIM; kk += 32) {
        // ---- stage A (fuse gather, already bf16): one row per thread ----
        {
            const uint4* fr = (const uint4*)(frow + kk);
            uint4 a0 = fr[0], a1 = fr[1], a2 = fr[2], a3 = fr[3];
            *(uint4*)&As[tid][0]  = a0;
            *(uint4*)&As[tid][8]  = a1;
            *(uint4*)&As[tid][16] = a2;
            *(uint4*)&As[tid][24] = a3;
        }
        // ---- stage B (wd): threads 0..127 ----
        if (tid < 128) {
            const int n  = tid & 31;
            const int k8 = tid >> 5;
            const float* bp = wd_e + (size_t)(kk + k8 * 8) * DDIM + d0 + n;
            bf16x8 p;
#pragma unroll
            for (int j = 0; j < 8; ++j) p[j] = (bf16_t)bp[(size_t)j * DDIM];
            *(bf16x8*)&Bs[n][k8 * 8] = p;
        }
        __syncthreads();

        bf16x8 af[4];
#pragma unroll
        for (int mt = 0; mt < 4; ++mt)
            af[mt] = *(const bf16x8*)&As[wave * 64 + mt * 16 + r][q * 8];
        bf16x8 bf_[2];
#pragma unroll
        for (int nt = 0; nt < 2; ++nt)
            bf_[nt] = *(const bf16x8*)&Bs[nt * 16 + r][q * 8];
#pragma unroll
        for (int mt = 0; mt < 4; ++mt)
#pragma unroll
            for (int nt = 0; nt < 2; ++nt)
                acc[mt][nt] = __builtin_amdgcn_mfma_f32_16x16x32_bf16(af[mt], bf_[nt], acc[mt][nt], 0, 0, 0);
        __syncthreads();
    }

#pragma unroll
    for (int mt = 0; mt < 4; ++mt) {
#pragma unroll
        for (int j = 0; j < 4; ++j) {
            const int m = wave * 64 + mt * 16 + q * 4 + j;
            const int em = sem[m];
            if (em < 0) continue;
            const int t = em >> 1;
            const int slot = em & 1;
            const float w = sw[m];
            float* dst = partial + ((size_t)slot * T_TOK + t) * DDIM + d0;
#pragma unroll
            for (int nt = 0; nt < 2; ++nt)
                dst[nt * 16 + r] = acc[mt][nt][j] * w;
        }
    }
}

// ---------------- phase 3: out = partial[0] + partial[1] ----------------
__global__ __launch_bounds__(256) void add_kernel(
    const float* __restrict__ partial, float* __restrict__ out)
{
    const int i = blockIdx.x * blockDim.x + threadIdx.x;   // over T*D/4
    const float4 a = ((const float4*)partial)[i];
    const float4 b = ((const float4*)(partial + (size_t)T_TOK * DDIM))[i];
    float4 o;
    o.x = a.x + b.x; o.y = a.y + b.y; o.z = a.z + b.z; o.w = a.w + b.w;
    ((float4*)out)[i] = o;
}

extern "C" void kernel_launch(void* const* d_in, const int* in_sizes, int n_in,
                              void* d_out, int out_size, void* d_ws, size_t ws_size,
                              hipStream_t stream) {
    const float* x  = (const float*)d_in[0];
    const float* rw = (const float*)d_in[1];
    const float* wg = (const float*)d_in[2];
    const float* wu = (const float*)d_in[3];
    const float* wd = (const float*)d_in[4];
    float* out = (float*)d_out;

    char* ws = (char*)d_ws;
    int*    cnt     = (int*)ws;
    int*    entry   = (int*)(ws + WS_ENTRY_OFF);
    float*  entry_w = (float*)(ws + WS_ENTRYW_OFF);
    bf16_t* fuse    = (bf16_t*)(ws + WS_FUSE_OFF);
    float*  partial = (float*)(ws + WS_PART_OFF);

    hipMemsetAsync(cnt, 0, 1024, stream);

    router_kernel<<<T_TOK, 64, 0, stream>>>(x, rw, cnt, entry, entry_w);

    ffn1_kernel<<<dim3(NEXP, FDIM / 64, 4), 256, 0, stream>>>(
        x, wg, wu, cnt, entry, fuse);

    ffn2_kernel<<<dim3(NEXP, DDIM / 32, 4), 256, 0, stream>>>(
        fuse, wd, cnt, entry, entry_w, partial);

    add_kernel<<<(T_TOK * DDIM / 4) / 256, 256, 0, stream>>>(partial, out);
}

// Round 3
// 443.766 us; speedup vs baseline: 3.0702x; 1.1804x over previous
//
#include <hip/hip_runtime.h>
#include <hip/hip_bf16.h>

typedef __bf16 bf16_t;
typedef __bf16 bf16x8 __attribute__((ext_vector_type(8)));
typedef __bf16 bf16x4 __attribute__((ext_vector_type(4)));
typedef float  f32x4  __attribute__((ext_vector_type(4)));

#define T_TOK 1024
#define DDIM  1024
#define FDIM  2048
#define NEXP  16
#define MAXR  192   // max tokens handled per expert (cnt ~ 128 +/- 11)

// ---------------- workspace layout (bytes), peak 21.1 MB ----------------
// [0, 64)        : int cnt[NEXP]                (memset each call)
// [1024, +64K)   : int   entry[NEXP][T_TOK]     (value = t*2 + slot)
// [66560, +64K)  : float entry_w[NEXP][T_TOK]
// [132096, +8M)  : OVERLAY: xg[NEXP][MAXR][DDIM] bf16 (gather..ffn1)
//                  then    partial[2][T_TOK][DDIM] f32 (ffn2..add)
// [8520704, +12.6M): bf16 fuse[NEXP][MAXR][FDIM]
#define WS_ENTRY_OFF   1024
#define WS_ENTRYW_OFF  66560
#define WS_XG_OFF      132096
#define WS_PART_OFF    132096
#define WS_FUSE_OFF    8520704

#define GLL16(g, l) __builtin_amdgcn_global_load_lds(                      \
    (const __attribute__((address_space(1))) unsigned int*)(g),            \
    (__attribute__((address_space(3))) unsigned int*)(l), 16, 0, 0)

// ---------------- router: one block (64 thr) per token ----------------
__global__ __launch_bounds__(64) void router_kernel(
    const float* __restrict__ x, const float* __restrict__ rw,
    int* __restrict__ cnt, int* __restrict__ entry, float* __restrict__ entry_w)
{
    const int t = blockIdx.x;
    const int lane = threadIdx.x;   // 0..63
    float acc[NEXP];
#pragma unroll
    for (int e = 0; e < NEXP; ++e) acc[e] = 0.f;
#pragma unroll
    for (int i = 0; i < DDIM / 64; ++i) {
        const int d = lane + i * 64;
        const float xv = x[(size_t)t * DDIM + d];
        const float* r = rw + (size_t)d * NEXP;
#pragma unroll
        for (int e = 0; e < NEXP; ++e) acc[e] += xv * r[e];
    }
#pragma unroll
    for (int e = 0; e < NEXP; ++e) {
        float v = acc[e];
        for (int off = 32; off > 0; off >>= 1) v += __shfl_down(v, off);
        acc[e] = v;
    }
    if (lane == 0) {
        int i0 = -1, i1 = -1;
        float v0 = -1e30f, v1 = -1e30f;
#pragma unroll
        for (int e = 0; e < NEXP; ++e) {
            const float v = acc[e];
            if (v > v0)      { v1 = v0; i1 = i0; v0 = v; i0 = e; }
            else if (v > v1) { v1 = v;  i1 = e; }
        }
        const float e1 = __expf(v1 - v0);
        const float w0 = 1.f / (1.f + e1);
        const float w1 = e1 / (1.f + e1);
        int p = atomicAdd(&cnt[i0], 1);
        entry[i0 * T_TOK + p] = t * 2 + 0;
        entry_w[i0 * T_TOK + p] = w0;
        p = atomicAdd(&cnt[i1], 1);
        entry[i1 * T_TOK + p] = t * 2 + 1;
        entry_w[i1 * T_TOK + p] = w1;
    }
}

// ---------------- gather: x -> expert-local bf16 xg[e][i][d] ----------------
// grid (NEXP, MAXR/32), 256 thr; one float4 per thread per row (coalesced).
__global__ __launch_bounds__(256) void gather_kernel(
    const float* __restrict__ x, const int* __restrict__ cnt,
    const int* __restrict__ entry, bf16_t* __restrict__ xg)
{
    const int e  = blockIdx.x;
    const int i0 = blockIdx.y * 32;
    const int tid = threadIdx.x;
    int n_tok = cnt[e]; if (n_tok > MAXR) n_tok = MAXR;
    for (int rr = 0; rr < 32; ++rr) {
        const int i = i0 + rr;
        bf16x4 v4;
        v4[0] = (bf16_t)0.f; v4[1] = (bf16_t)0.f; v4[2] = (bf16_t)0.f; v4[3] = (bf16_t)0.f;
        if (i < n_tok) {
            const int tok = entry[e * T_TOK + i] >> 1;
            const float4 v = *(const float4*)(x + (size_t)tok * DDIM + tid * 4);
            v4[0] = (bf16_t)v.x; v4[1] = (bf16_t)v.y; v4[2] = (bf16_t)v.z; v4[3] = (bf16_t)v.w;
        }
        *(bf16x4*)(xg + ((size_t)e * MAXR + i) * DDIM + tid * 4) = v4;
    }
}

// ---------------- phase 1: gating+up MFMA GEMM + silu-fuse ----------------
// grid (NEXP, FDIM/64), 256 thr. BM=192, BN=64, BK=32. reg-prefetch dbuf.
__global__ __launch_bounds__(256, 2) void ffn1_kernel(
    const bf16_t* __restrict__ xg,
    const float* __restrict__ wg, const float* __restrict__ wu,
    const int* __restrict__ cnt, const int* __restrict__ entry,
    bf16_t* __restrict__ fuse)
{
    const int e  = blockIdx.x;
    const int f0 = blockIdx.y * 64;
    int n_tok = cnt[e]; if (n_tok > MAXR) n_tok = MAXR;

    __shared__ __align__(16) bf16_t As[2][MAXR][32];   // 24 KB
    __shared__ __align__(16) bf16_t Bgs[2][64][40];    // 10 KB (pad 8 -> bank-spread)
    __shared__ __align__(16) bf16_t Bus[2][64][40];    // 10 KB
    __shared__ int sem[MAXR];

    const int tid  = threadIdx.x;
    const int wave = tid >> 6;
    const int lane = tid & 63;
    const int r    = lane & 15;
    const int q    = lane >> 4;

    const bf16_t* xg_e = xg + (size_t)e * MAXR * DDIM;
    const float* wg_p = wg + (size_t)e * DDIM * FDIM + (size_t)(wave * 8) * FDIM + f0 + lane;
    const float* wu_p = wu + (size_t)e * DDIM * FDIM + (size_t)(wave * 8) * FDIM + f0 + lane;

    if (tid < MAXR) sem[tid] = (tid < n_tok) ? entry[e * T_TOK + tid] : -1;

    // prologue: B(0) into regs, A(0) into LDS buf 0
    float rg[8], ru[8];
#pragma unroll
    for (int j = 0; j < 8; ++j) { rg[j] = wg_p[(size_t)j * FDIM]; ru[j] = wu_p[(size_t)j * FDIM]; }
#pragma unroll
    for (int c = 0; c < 3; ++c) {
        const int rowb = wave * 48 + c * 16;
        const bf16_t* g = xg_e + (size_t)(rowb + (lane >> 2)) * DDIM + (lane & 3) * 8;
        GLL16(g, &As[0][rowb][0] + lane * 8);
    }

    f32x4 accg[3][4], accu[3][4];
#pragma unroll
    for (int a = 0; a < 3; ++a)
#pragma unroll
        for (int b = 0; b < 4; ++b) {
            accg[a][b] = (f32x4){0.f, 0.f, 0.f, 0.f};
            accu[a][b] = (f32x4){0.f, 0.f, 0.f, 0.f};
        }

    for (int i = 0; i < 32; ++i) {
        const int buf = i & 1;
        // pack current B regs -> LDS (single b128 write per matrix)
        bf16x8 pg, pu;
#pragma unroll
        for (int j = 0; j < 8; ++j) { pg[j] = (bf16_t)rg[j]; pu[j] = (bf16_t)ru[j]; }
        *(bf16x8*)&Bgs[buf][lane][wave * 8] = pg;
        *(bf16x8*)&Bus[buf][lane][wave * 8] = pu;
        __syncthreads();   // A(i)+B(i) now resident (barrier drains glls)
        if (i < 31) {
            // prefetch B(i+1) regs and A(i+1) -> other LDS buffer
            wg_p += (size_t)32 * FDIM; wu_p += (size_t)32 * FDIM;
#pragma unroll
            for (int j = 0; j < 8; ++j) { rg[j] = wg_p[(size_t)j * FDIM]; ru[j] = wu_p[(size_t)j * FDIM]; }
            const int kk = (i + 1) * 32;
#pragma unroll
            for (int c = 0; c < 3; ++c) {
                const int rowb = wave * 48 + c * 16;
                const bf16_t* g = xg_e + (size_t)(rowb + (lane >> 2)) * DDIM + kk + (lane & 3) * 8;
                GLL16(g, &As[buf ^ 1][rowb][0] + lane * 8);
            }
        }
        // fragments + MFMA on buffer `buf`
        bf16x8 af[3];
#pragma unroll
        for (int mt = 0; mt < 3; ++mt)
            af[mt] = *(const bf16x8*)&As[buf][wave * 48 + mt * 16 + r][q * 8];
        bf16x8 bg[4], bu[4];
#pragma unroll
        for (int nt = 0; nt < 4; ++nt) {
            bg[nt] = *(const bf16x8*)&Bgs[buf][nt * 16 + r][q * 8];
            bu[nt] = *(const bf16x8*)&Bus[buf][nt * 16 + r][q * 8];
        }
#pragma unroll
        for (int mt = 0; mt < 3; ++mt)
#pragma unroll
            for (int nt = 0; nt < 4; ++nt) {
                accg[mt][nt] = __builtin_amdgcn_mfma_f32_16x16x32_bf16(af[mt], bg[nt], accg[mt][nt], 0, 0, 0);
                accu[mt][nt] = __builtin_amdgcn_mfma_f32_16x16x32_bf16(af[mt], bu[nt], accu[mt][nt], 0, 0, 0);
            }
        // no trailing barrier: next iter writes the other buffer; the next
        // barrier's lgkm drain protects this iter's ds_reads.
    }

    // epilogue: silu(g)*u -> fuse[e][m][f] (bf16), zeros for padded rows
    bf16_t* fuse_e = fuse + (size_t)e * MAXR * FDIM + f0;
#pragma unroll
    for (int mt = 0; mt < 3; ++mt) {
#pragma unroll
        for (int j = 0; j < 4; ++j) {
            const int m = wave * 48 + mt * 16 + q * 4 + j;
            const bool valid = sem[m] >= 0;
            bf16_t* dst = fuse_e + (size_t)m * FDIM;
#pragma unroll
            for (int nt = 0; nt < 4; ++nt) {
                const float g = accg[mt][nt][j];
                const float u = accu[mt][nt][j];
                const float h = valid ? (g / (1.f + __expf(-g))) * u : 0.f;
                dst[nt * 16 + r] = (bf16_t)h;
            }
        }
    }
}

// ---------------- phase 2: down MFMA GEMM, weighted -> partial ----------------
// grid (NEXP, DDIM/32), 256 thr. BM=192, BN=32, BK=64 (two 32-wide halves).
__global__ __launch_bounds__(256, 2) void ffn2_kernel(
    const bf16_t* __restrict__ fuse, const float* __restrict__ wd,
    const int* __restrict__ cnt, const int* __restrict__ entry,
    const float* __restrict__ entry_w, float* __restrict__ partial)
{
    const int e  = blockIdx.x;
    const int d0 = blockIdx.y * 32;
    int n_tok = cnt[e]; if (n_tok > MAXR) n_tok = MAXR;

    __shared__ __align__(16) bf16_t As[2][2][MAXR][32];  // [buf][khalf][m][k] 48 KB
    __shared__ __align__(16) bf16_t Bs[2][32][72];       // 9 KB (pad 8)
    __shared__ int   sem[MAXR];
    __shared__ float sw[MAXR];

    const int tid  = threadIdx.x;
    const int wave = tid >> 6;
    const int lane = tid & 63;
    const int r    = lane & 15;
    const int q    = lane >> 4;

    const bf16_t* fu_e = fuse + (size_t)e * MAXR * FDIM;
    const int bn = tid & 31;
    const int k8 = (tid >> 5) * 8;
    const float* wd_p = wd + (size_t)e * FDIM * DDIM + (size_t)k8 * DDIM + d0 + bn;

    if (tid < MAXR) {
        sem[tid] = (tid < n_tok) ? entry[e * T_TOK + tid] : -1;
        sw[tid]  = (tid < n_tok) ? entry_w[e * T_TOK + tid] : 0.f;
    }

    float rb[8];
#pragma unroll
    for (int j = 0; j < 8; ++j) rb[j] = wd_p[(size_t)j * DDIM];
#pragma unroll
    for (int ks = 0; ks < 2; ++ks)
#pragma unroll
        for (int c = 0; c < 3; ++c) {
            const int rowb = wave * 48 + c * 16;
            const bf16_t* g = fu_e + (size_t)(rowb + (lane >> 2)) * FDIM + ks * 32 + (lane & 3) * 8;
            GLL16(g, &As[0][ks][rowb][0] + lane * 8);
        }

    f32x4 acc[3][2];
#pragma unroll
    for (int a = 0; a < 3; ++a)
#pragma unroll
        for (int b = 0; b < 2; ++b) acc[a][b] = (f32x4){0.f, 0.f, 0.f, 0.f};

    for (int i = 0; i < 32; ++i) {
        const int buf = i & 1;
        bf16x8 pb;
#pragma unroll
        for (int j = 0; j < 8; ++j) pb[j] = (bf16_t)rb[j];
        *(bf16x8*)&Bs[buf][bn][k8] = pb;
        __syncthreads();
        if (i < 31) {
            wd_p += (size_t)64 * DDIM;
#pragma unroll
            for (int j = 0; j < 8; ++j) rb[j] = wd_p[(size_t)j * DDIM];
            const int kk = (i + 1) * 64;
#pragma unroll
            for (int ks = 0; ks < 2; ++ks)
#pragma unroll
                for (int c = 0; c < 3; ++c) {
                    const int rowb = wave * 48 + c * 16;
                    const bf16_t* g = fu_e + (size_t)(rowb + (lane >> 2)) * FDIM + kk + ks * 32 + (lane & 3) * 8;
                    GLL16(g, &As[buf ^ 1][ks][rowb][0] + lane * 8);
                }
        }
#pragma unroll
        for (int ks = 0; ks < 2; ++ks) {
            bf16x8 af[3], bb[2];
#pragma unroll
            for (int mt = 0; mt < 3; ++mt)
                af[mt] = *(const bf16x8*)&As[buf][ks][wave * 48 + mt * 16 + r][q * 8];
#pragma unroll
            for (int nt = 0; nt < 2; ++nt)
                bb[nt] = *(const bf16x8*)&Bs[buf][nt * 16 + r][ks * 32 + q * 8];
#pragma unroll
            for (int mt = 0; mt < 3; ++mt)
#pragma unroll
                for (int nt = 0; nt < 2; ++nt)
                    acc[mt][nt] = __builtin_amdgcn_mfma_f32_16x16x32_bf16(af[mt], bb[nt], acc[mt][nt], 0, 0, 0);
        }
    }

#pragma unroll
    for (int mt = 0; mt < 3; ++mt) {
#pragma unroll
        for (int j = 0; j < 4; ++j) {
            const int m = wave * 48 + mt * 16 + q * 4 + j;
            const int em = sem[m];
            if (em < 0) continue;
            const int t = em >> 1;
            const int slot = em & 1;
            const float w = sw[m];
            float* dst = partial + ((size_t)slot * T_TOK + t) * DDIM + d0;
#pragma unroll
            for (int nt = 0; nt < 2; ++nt)
                dst[nt * 16 + r] = acc[mt][nt][j] * w;
        }
    }
}

// ---------------- phase 3: out = partial[0] + partial[1] ----------------
__global__ __launch_bounds__(256) void add_kernel(
    const float* __restrict__ partial, float* __restrict__ out)
{
    const int i = blockIdx.x * blockDim.x + threadIdx.x;   // over T*D/4
    const float4 a = ((const float4*)partial)[i];
    const float4 b = ((const float4*)(partial + (size_t)T_TOK * DDIM))[i];
    float4 o;
    o.x = a.x + b.x; o.y = a.y + b.y; o.z = a.z + b.z; o.w = a.w + b.w;
    ((float4*)out)[i] = o;
}

extern "C" void kernel_launch(void* const* d_in, const int* in_sizes, int n_in,
                              void* d_out, int out_size, void* d_ws, size_t ws_size,
                              hipStream_t stream) {
    const float* x  = (const float*)d_in[0];
    const float* rw = (const float*)d_in[1];
    const float* wg = (const float*)d_in[2];
    const float* wu = (const float*)d_in[3];
    const float* wd = (const float*)d_in[4];
    float* out = (float*)d_out;

    char* ws = (char*)d_ws;
    int*    cnt     = (int*)ws;
    int*    entry   = (int*)(ws + WS_ENTRY_OFF);
    float*  entry_w = (float*)(ws + WS_ENTRYW_OFF);
    bf16_t* xg      = (bf16_t*)(ws + WS_XG_OFF);
    float*  partial = (float*)(ws + WS_PART_OFF);   // overlays xg (disjoint lifetime)
    bf16_t* fuse    = (bf16_t*)(ws + WS_FUSE_OFF);

    hipMemsetAsync(cnt, 0, 64, stream);

    router_kernel<<<T_TOK, 64, 0, stream>>>(x, rw, cnt, entry, entry_w);

    gather_kernel<<<dim3(NEXP, MAXR / 32), 256, 0, stream>>>(x, cnt, entry, xg);

    ffn1_kernel<<<dim3(NEXP, FDIM / 64), 256, 0, stream>>>(
        xg, wg, wu, cnt, entry, fuse);

    ffn2_kernel<<<dim3(NEXP, DDIM / 32), 256, 0, stream>>>(
        fuse, wd, cnt, entry, entry_w, partial);

    add_kernel<<<(T_TOK * DDIM / 4) / 256, 256, 0, stream>>>(partial, out);
}